// Round 19
// baseline (107.427 us; speedup 1.0000x reference)
//
#include <hip/hip_runtime.h>
#include <hip/hip_bf16.h>

typedef __attribute__((ext_vector_type(4))) float f32x4;
typedef __attribute__((ext_vector_type(16))) float f32x16;
typedef __attribute__((ext_vector_type(8))) short short8;
typedef __attribute__((ext_vector_type(8))) unsigned short ushort8;
typedef __attribute__((ext_vector_type(4))) unsigned int u32x4;
typedef __attribute__((ext_vector_type(2))) unsigned int u32x2;
typedef unsigned short u16;

__device__ __forceinline__ u16 f2bf(float x) {
  unsigned u = __float_as_uint(x);
  u += 0x7fffu + ((u >> 16) & 1u);   // RNE
  return (u16)(u >> 16);
}
__device__ __forceinline__ float bf2f(u16 v) {
  return __uint_as_float(((unsigned)v) << 16);
}

__device__ __forceinline__ void gload_lds16(const void* g, void* l) {
  __builtin_amdgcn_global_load_lds(
      (__attribute__((address_space(1))) void*)g,
      (__attribute__((address_space(3))) void*)l, 16, 0, 0);
}

// -------------------- fp32 -> bf16 convert (all 3 inputs, one kernel) -------------
__global__ void cvt_all(const float* __restrict__ x, const float* __restrict__ wq,
                        const float* __restrict__ wp, ushort4* __restrict__ dst) {
  const int N1 = 1048576, N2 = 786432, NT = 2097152;
  for (int i = blockIdx.x * 256 + threadIdx.x; i < NT; i += 524288) {
    float4 v;
    if (i < N1)            v = ((const float4*)x)[i];
    else if (i < N1 + N2)  v = ((const float4*)wq)[i - N1];
    else                   v = ((const float4*)wp)[i - N1 - N2];
    ushort4 o;
    o.x = f2bf(v.x); o.y = f2bf(v.y); o.z = f2bf(v.z); o.w = f2bf(v.w);
    dst[i] = o;
  }
}

// ==================== 128x192 GEMM (QKV): C = A B^T + bias, bf16 out ==============
// (frozen from R13)
__global__ __launch_bounds__(512, 4) void gemm128_bt(
    const u16* __restrict__ A, const u16* __restrict__ B,
    const float* __restrict__ bias, u16* __restrict__ Cout,
    int M, int N, int K)
{
  __shared__ u16 LA[2][8192];    // [buf][128 x 64]
  __shared__ u16 LB[2][12288];   // [buf][192 x 64]

  const int tid  = threadIdx.x;
  const int w    = tid >> 6;        // 0..7
  const int lane = tid & 63;
  const int wm   = w >> 2;          // 0..1
  const int wn   = w & 3;           // 0..3
  const int hi   = lane >> 4;       // 0..3
  const int lo   = lane & 15;
  const int l7   = lo & 7;

  const int L  = (int)(blockIdx.x & 7) * 64 + (int)(blockIdx.x >> 3);
  const int bx = L >> 5, by = L & 31;
  const long brow = (long)by * 128;
  const long bcol = (long)bx * 192;

  f32x4 acc[4][3];
#pragma unroll
  for (int f = 0; f < 4; ++f)
#pragma unroll
    for (int n = 0; n < 3; ++n)
#pragma unroll
      for (int r = 0; r < 4; ++r) acc[f][n][r] = 0.0f;

  const int srow = lane >> 3;
  const int sg   = (lane & 7) ^ srow;

  auto stage = [&](int kt, int bi) {
    const long k0 = (long)kt * 64;
#pragma unroll
    for (int i = 0; i < 2; ++i) {
      const long r = brow + i * 64 + w * 8 + srow;
      gload_lds16(A + r * K + k0 + sg * 8, &LA[bi][i * 4096 + w * 512]);
    }
#pragma unroll
    for (int u = 0; u < 3; ++u) {
      const long r = bcol + u * 64 + w * 8 + srow;
      gload_lds16(B + r * K + k0 + sg * 8, &LB[bi][u * 4096 + w * 512]);
    }
  };

  const int nkt = K >> 6;   // 16
  stage(0, 0); stage(1, 1);
  asm volatile("s_waitcnt vmcnt(5)" ::: "memory");
  __builtin_amdgcn_s_barrier();

  for (int t = 0; t < nkt; ++t) {
    const int bi = t & 1;
    short8 a[4][2], b[3][2];
#pragma unroll
    for (int f = 0; f < 4; ++f) {
      const int rl = wm * 64 + f * 16 + lo;
#pragma unroll
      for (int ks = 0; ks < 2; ++ks)
        a[f][ks] = *(const short8*)(&LA[bi][rl * 64 + ((ks * 4 + hi) ^ l7) * 8]);
    }
#pragma unroll
    for (int n = 0; n < 3; ++n) {
      const int rl = wn * 48 + n * 16 + lo;
#pragma unroll
      for (int ks = 0; ks < 2; ++ks)
        b[n][ks] = *(const short8*)(&LB[bi][rl * 64 + ((ks * 4 + hi) ^ l7) * 8]);
    }
    asm volatile("s_waitcnt lgkmcnt(0)" ::: "memory");
    __builtin_amdgcn_sched_barrier(0);
    __builtin_amdgcn_s_barrier();
    if (t + 2 < nkt) stage(t + 2, bi);
    __builtin_amdgcn_s_setprio(1);
#pragma unroll
    for (int f = 0; f < 4; ++f)
#pragma unroll
      for (int n = 0; n < 3; ++n)
#pragma unroll
        for (int ks = 0; ks < 2; ++ks)
          acc[f][n] = __builtin_amdgcn_mfma_f32_16x16x32_bf16(a[f][ks], b[n][ks], acc[f][n], 0, 0, 0);
    __builtin_amdgcn_s_setprio(0);
    if (t + 2 < nkt)      { asm volatile("s_waitcnt vmcnt(5)" ::: "memory"); }
    else if (t + 1 < nkt) { asm volatile("s_waitcnt vmcnt(0)" ::: "memory"); }
    __builtin_amdgcn_sched_barrier(0);
    __builtin_amdgcn_s_barrier();
  }

  const float SCC = 0.18033688011112042f;   // 0.125 * log2(e)
  float bv[3];
#pragma unroll
  for (int n = 0; n < 3; ++n) bv[n] = bias[bcol + wn * 48 + n * 16 + lo];
#pragma unroll
  for (int f = 0; f < 4; ++f)
#pragma unroll
    for (int n = 0; n < 3; ++n) {
      const long colf = bcol + wn * 48 + n * 16;
      const float qsc = (colf < 1024) ? SCC : 1.0f;   // q/k boundary at 1024
#pragma unroll
      for (int r = 0; r < 4; ++r) {
        const long row = brow + wm * 64 + f * 16 + hi * 4 + r;
        Cout[row * (long)N + colf + lo] = f2bf((acc[f][n][r] + bv[n]) * qsc);
      }
    }
}

// ==================== 64x64 GEMM (proj): C = A B^T + bias, fp32 out ===============
// (frozen from R17)
__global__ __launch_bounds__(256, 2) void gemm_proj(
    const u16* __restrict__ A, const u16* __restrict__ B,
    const float* __restrict__ bias, float* __restrict__ Cout,
    int M, int N, int K)
{
  __shared__ u16 LA[2][4096];   // [buf][64 x 64]
  __shared__ u16 LB[2][4096];   // [buf][64 x 64]

  const int tid  = threadIdx.x;
  const int w    = tid >> 6;        // 0..3
  const int lane = tid & 63;
  const int wm   = w >> 1;
  const int wn   = w & 1;
  const int hi   = lane >> 4;
  const int lo   = lane & 15;
  const int l7   = lo & 7;

  const int L  = (int)(blockIdx.x & 7) * 128 + (int)(blockIdx.x >> 3);
  const int bx = L >> 6, by = L & 63;
  const long brow = (long)by * 64;
  const long bcol = (long)bx * 64;

  f32x4 acc[2][2];
#pragma unroll
  for (int f = 0; f < 2; ++f)
#pragma unroll
    for (int n = 0; n < 2; ++n)
#pragma unroll
      for (int r = 0; r < 4; ++r) acc[f][n][r] = 0.0f;

  const int srow = lane >> 3;
  const int sg   = (lane & 7) ^ srow;

  auto stage = [&](int kt, int bi) {
    const long k0 = (long)kt * 64;
#pragma unroll
    for (int c = 0; c < 2; ++c) {
      const long r = brow + c * 32 + w * 8 + srow;
      gload_lds16(A + r * K + k0 + sg * 8, &LA[bi][c * 2048 + w * 512]);
    }
#pragma unroll
    for (int c = 0; c < 2; ++c) {
      const long r = bcol + c * 32 + w * 8 + srow;
      gload_lds16(B + r * K + k0 + sg * 8, &LB[bi][c * 2048 + w * 512]);
    }
  };

  const int nkt = K >> 6;   // 16
  stage(0, 0); stage(1, 1);
  asm volatile("s_waitcnt vmcnt(4)" ::: "memory");
  __builtin_amdgcn_s_barrier();

  for (int t = 0; t < nkt; ++t) {
    const int bi = t & 1;
    short8 a[2][2], b[2][2];
#pragma unroll
    for (int f = 0; f < 2; ++f) {
      const int rl = wm * 32 + f * 16 + lo;
#pragma unroll
      for (int ks = 0; ks < 2; ++ks)
        a[f][ks] = *(const short8*)(&LA[bi][rl * 64 + ((ks * 4 + hi) ^ l7) * 8]);
    }
#pragma unroll
    for (int n = 0; n < 2; ++n) {
      const int rl = wn * 32 + n * 16 + lo;
#pragma unroll
      for (int ks = 0; ks < 2; ++ks)
        b[n][ks] = *(const short8*)(&LB[bi][rl * 64 + ((ks * 4 + hi) ^ l7) * 8]);
    }
    asm volatile("s_waitcnt lgkmcnt(0)" ::: "memory");
    __builtin_amdgcn_sched_barrier(0);
    __builtin_amdgcn_s_barrier();
    if (t + 2 < nkt) stage(t + 2, bi);
    __builtin_amdgcn_s_setprio(1);
#pragma unroll
    for (int f = 0; f < 2; ++f)
#pragma unroll
      for (int n = 0; n < 2; ++n)
#pragma unroll
        for (int ks = 0; ks < 2; ++ks)
          acc[f][n] = __builtin_amdgcn_mfma_f32_16x16x32_bf16(a[f][ks], b[n][ks], acc[f][n], 0, 0, 0);
    __builtin_amdgcn_s_setprio(0);
    if (t + 2 < nkt)      { asm volatile("s_waitcnt vmcnt(4)" ::: "memory"); }
    else if (t + 1 < nkt) { asm volatile("s_waitcnt vmcnt(0)" ::: "memory"); }
    __builtin_amdgcn_sched_barrier(0);
    __builtin_amdgcn_s_barrier();
  }

  float bv[2];
#pragma unroll
  for (int n = 0; n < 2; ++n) bv[n] = bias[bcol + wn * 32 + n * 16 + lo];
#pragma unroll
  for (int f = 0; f < 2; ++f)
#pragma unroll
    for (int n = 0; n < 2; ++n)
#pragma unroll
      for (int r = 0; r < 4; ++r) {
        const long row = brow + wm * 32 + f * 16 + hi * 4 + r;
        const long col = bcol + wn * 32 + n * 16 + lo;
        Cout[row * (long)N + col] = acc[f][n][r] + bv[n];
      }
}

// -------------------- fused flash attention (R10 inner loop, 4-way KV split) ------
// Grid 1024 = 16 qb x 32 bh x 2 kv-groups (R3's split-across-grid, 2->4 way).
// Block structure byte-identical to frozen R10 (8 warps = 4 qg x 2 halves), but
// each half covers 512 keys (8 tiles): keys [g*1024 + half*512, +512).
// LDS 48 KB -> 3 blocks/CU resident = 24 waves/CU (was 2 blocks = 16).
// Epilogue writes UNNORMALIZED bf16 O-partial + fp32 l (additive, shift-free
// softmax); attn_merge sums the 2 groups and normalizes.
__global__ __launch_bounds__(512, 4) void attn_fused(
    const u16* __restrict__ qkv, u16* __restrict__ opart0,
    u16* __restrict__ opart1, float* __restrict__ lpart)
{
  __shared__ __align__(16) char smem[49152];

  const int tid  = threadIdx.x;
  const int w    = tid >> 6;
  const int lane = tid & 63;
  const int l31  = lane & 31;
  const int hc   = lane >> 5;        // wave half
  const int g1   = (lane >> 4) & 1;  // d16 select for tr-read
  const int l15  = lane & 15;
  const int half = w >> 2;           // KV sub-half within group
  const int qg   = w & 3;            // q subgroup (32 rows)

  const int bid  = blockIdx.x;       // 0..1023
  const int xcd  = bid & 7;
  const int slot = bid >> 3;         // 0..127
  const int g    = slot & 1;         // kv group (keys g*1024 .. +1024)
  const int rest = slot >> 1;        // 0..63
  const int qb   = rest & 15;
  const int bh   = ((rest >> 4) << 3) | xcd;
  const int b    = bh >> 4, h = bh & 15;

  short8 qf[4];
  {
    const u16* qp = qkv + (size_t)(b * 2048 + qb * 128 + qg * 32 + l31) * 3072 + h * 64 + hc * 8;
#pragma unroll
    for (int ds = 0; ds < 4; ++ds) qf[ds] = *(const short8*)(qp + ds * 16);
  }

  f32x16 acc0, acc1;
#pragma unroll
  for (int r = 0; r < 16; ++r) { acc0[r] = 0.f; acc1[r] = 0.f; }
  float lsum = 0.f;

  const int srow8 = lane >> 3;
  const int kgl   = (lane & 7) ^ srow8;
  const int vkey  = (lane >> 5) * 4 + ((lane >> 1) & 3);
  const int vd    = ((lane >> 3) & 3) * 16 + (lane & 1) * 8;

  auto kbuf = [&](int bi) { return (u16*)(smem + (size_t)(half * 2 + bi) * 8192); };
  u16* vb = (u16*)(smem + 32768 + (size_t)half * 8192);

  const size_t kvbase = (size_t)(b * 2048 + g * 1024 + half * 512);

  auto stK = [&](int t, int bi) {
    const size_t rbase = kvbase + t * 64;
    u16* Kb = kbuf(bi);
#pragma unroll
    for (int c = 0; c < 2; ++c) {
      const int chunk = qg * 2 + c;
      gload_lds16(qkv + (rbase + chunk * 8 + srow8) * 3072 + 1024 + h * 64 + kgl * 8,
                  Kb + chunk * 512);
    }
  };
  auto stV = [&](int t) {
    const size_t rbase = kvbase + t * 64;
#pragma unroll
    for (int c = 0; c < 2; ++c) {
      const int chunk = qg * 2 + c;
      gload_lds16(qkv + (rbase + chunk * 8 + vkey) * 3072 + 2048 + h * 64 + vd,
                  vb + chunk * 512);
    }
  };

  stK(0, 0); stV(0);
  asm volatile("s_waitcnt vmcnt(0)" ::: "memory");
  __builtin_amdgcn_s_barrier();
  int cur = 0;

  for (int t = 0; t < 8; ++t) {
    const bool pfK = t < 7;
    if (pfK) stK(t + 1, cur ^ 1);

    const u16* Kc = kbuf(cur);

    f32x16 s0, s1;
#pragma unroll
    for (int r = 0; r < 16; ++r) { s0[r] = 0.f; s1[r] = 0.f; }
    __builtin_amdgcn_s_setprio(1);
#pragma unroll
    for (int ds = 0; ds < 4; ++ds) {
      const int gb = (((2 * ds + hc) ^ (lane & 7)) << 4);
      const short8 k0 = *(const short8*)((const char*)Kc + l31 * 128 + gb);
      const short8 k1 = *(const short8*)((const char*)Kc + 4096 + l31 * 128 + gb);
      s0 = __builtin_amdgcn_mfma_f32_32x32x16_bf16(k0, qf[ds], s0, 0, 0, 0);
      s1 = __builtin_amdgcn_mfma_f32_32x32x16_bf16(k1, qf[ds], s1, 0, 0, 0);
    }
    __builtin_amdgcn_s_setprio(0);

    float p[32];
#pragma unroll
    for (int r = 0; r < 16; ++r) {
      p[r]      = __builtin_amdgcn_exp2f(s0[r]);
      p[16 + r] = __builtin_amdgcn_exp2f(s1[r]);
    }
    {
      float a0 = 0.f, a1 = 0.f, a2 = 0.f, a3 = 0.f;
#pragma unroll
      for (int r = 0; r < 8; ++r) {
        a0 += p[r]; a1 += p[8 + r]; a2 += p[16 + r]; a3 += p[24 + r];
      }
      lsum += (a0 + a1) + (a2 + a3);
    }

    short8 pa[4];
#pragma unroll
    for (int ks = 0; ks < 4; ++ks) {
      const int bs = ks * 8;
      unsigned X0, X1, X2, X3;
      asm("v_cvt_pk_bf16_f32 %0, %1, %2" : "=v"(X0) : "v"(p[bs + 0]), "v"(p[bs + 1]));
      asm("v_cvt_pk_bf16_f32 %0, %1, %2" : "=v"(X1) : "v"(p[bs + 2]), "v"(p[bs + 3]));
      asm("v_cvt_pk_bf16_f32 %0, %1, %2" : "=v"(X2) : "v"(p[bs + 4]), "v"(p[bs + 5]));
      asm("v_cvt_pk_bf16_f32 %0, %1, %2" : "=v"(X3) : "v"(p[bs + 6]), "v"(p[bs + 7]));
      asm("v_permlane32_swap_b32 %0, %1" : "+v"(X0), "+v"(X2));
      asm("v_permlane32_swap_b32 %0, %1" : "+v"(X1), "+v"(X3));
      u32x4 wv;
      wv[0] = X0; wv[1] = X1; wv[2] = X2; wv[3] = X3;
      pa[ks] = __builtin_bit_cast(short8, wv);
    }

    if (pfK) { asm volatile("s_waitcnt vmcnt(2)" ::: "memory"); }
    else     { asm volatile("s_waitcnt vmcnt(0)" ::: "memory"); }
    __builtin_amdgcn_sched_barrier(0);
    __builtin_amdgcn_s_barrier();

    {
      const unsigned va =
          (unsigned)(unsigned long long)(const __attribute__((address_space(3))) u16*)vb;
#pragma unroll
      for (int dt = 0; dt < 2; ++dt) {
        const unsigned vba = va + (unsigned)(hc * 1024 + dt * 256 + g1 * 128 + l15 * 8);
        u32x2 q0, q1, q2, q3, q4, q5, q6, q7;
        asm volatile("ds_read_b64_tr_b16 %0, %1"             : "=v"(q0) : "v"(vba));
        asm volatile("ds_read_b64_tr_b16 %0, %1 offset:512"  : "=v"(q1) : "v"(vba));
        asm volatile("ds_read_b64_tr_b16 %0, %1 offset:2048" : "=v"(q2) : "v"(vba));
        asm volatile("ds_read_b64_tr_b16 %0, %1 offset:2560" : "=v"(q3) : "v"(vba));
        asm volatile("ds_read_b64_tr_b16 %0, %1 offset:4096" : "=v"(q4) : "v"(vba));
        asm volatile("ds_read_b64_tr_b16 %0, %1 offset:4608" : "=v"(q5) : "v"(vba));
        asm volatile("ds_read_b64_tr_b16 %0, %1 offset:6144" : "=v"(q6) : "v"(vba));
        asm volatile("ds_read_b64_tr_b16 %0, %1 offset:6656" : "=v"(q7) : "v"(vba));
        asm volatile("s_waitcnt lgkmcnt(0)" ::: "memory");
        __builtin_amdgcn_sched_barrier(0);
        __builtin_amdgcn_s_setprio(1);
        f32x16 A = dt ? acc1 : acc0;
        {
          u32x4 bb; bb[0] = q0[0]; bb[1] = q0[1]; bb[2] = q1[0]; bb[3] = q1[1];
          A = __builtin_amdgcn_mfma_f32_32x32x16_bf16(pa[0], __builtin_bit_cast(short8, bb), A, 0, 0, 0);
        }
        {
          u32x4 bb; bb[0] = q2[0]; bb[1] = q2[1]; bb[2] = q3[0]; bb[3] = q3[1];
          A = __builtin_amdgcn_mfma_f32_32x32x16_bf16(pa[1], __builtin_bit_cast(short8, bb), A, 0, 0, 0);
        }
        {
          u32x4 bb; bb[0] = q4[0]; bb[1] = q4[1]; bb[2] = q5[0]; bb[3] = q5[1];
          A = __builtin_amdgcn_mfma_f32_32x32x16_bf16(pa[2], __builtin_bit_cast(short8, bb), A, 0, 0, 0);
        }
        {
          u32x4 bb; bb[0] = q6[0]; bb[1] = q6[1]; bb[2] = q7[0]; bb[3] = q7[1];
          A = __builtin_amdgcn_mfma_f32_32x32x16_bf16(pa[3], __builtin_bit_cast(short8, bb), A, 0, 0, 0);
        }
        __builtin_amdgcn_s_setprio(0);
        if (dt) acc1 = A; else acc0 = A;
      }
    }

    asm volatile("s_waitcnt vmcnt(0)" ::: "memory");
    __builtin_amdgcn_sched_barrier(0);
    __builtin_amdgcn_s_barrier();

    if (pfK) stV(t + 1);
    cur ^= 1;
  }

  // ---- merge the block's 2 sub-halves via LDS; write UNNORMALIZED partial ----
  float ltot = lsum + __shfl_xor(lsum, 32);
  float* MG = (float*)smem;
  const int midx = (qg * 64 + lane) * 33;
  if (half == 1) {
#pragma unroll
    for (int r = 0; r < 16; ++r) { MG[midx + r] = acc0[r]; MG[midx + 16 + r] = acc1[r]; }
    MG[midx + 32] = ltot;
  }
  __syncthreads();
  if (half == 0) {
#pragma unroll
    for (int r = 0; r < 16; ++r) { acc0[r] += MG[midx + r]; acc1[r] += MG[midx + 16 + r]; }
    ltot += MG[midx + 32];
    u16* op = g ? opart1 : opart0;
    const size_t orow0 = (size_t)(b * 2048 + qb * 128 + qg * 32);
#pragma unroll
    for (int r = 0; r < 16; ++r) {
      const int rowq = (r & 3) + 8 * (r >> 2) + 4 * hc;
      op[(orow0 + rowq) * 1024 + h * 64 + l31]      = f2bf(acc0[r]);
      op[(orow0 + rowq) * 1024 + h * 64 + 32 + l31] = f2bf(acc1[r]);
    }
    if (hc == 0)   // lanes 0..31: lane owns q-row l31's l-sum
      lpart[(size_t)g * 65536 + (orow0 + l31) * 16 + h] = ltot;
  }
}

// -------------------- merge: out = (O0 + O1) / (l0 + l1), bf16 --------------------
__global__ void attn_merge(const u16* __restrict__ o0, const u16* __restrict__ o1,
                           const float* __restrict__ lp, u16* __restrict__ out) {
  const int i = blockIdx.x * 256 + threadIdx.x;   // ushort8 index; 524288 total
  if (i >= 524288) return;
  const int e0  = i * 8;
  const int row = e0 >> 10;
  const int h   = (e0 & 1023) >> 6;
  const float inv = 1.0f / (lp[row * 16 + h] + lp[65536 + row * 16 + h]);
  const ushort8 a = *(const ushort8*)(o0 + e0);
  const ushort8 b = *(const ushort8*)(o1 + e0);
  ushort8 o;
#pragma unroll
  for (int j = 0; j < 8; ++j) o[j] = f2bf((bf2f(a[j]) + bf2f(b[j])) * inv);
  *(ushort8*)(out + e0) = o;
}

// -------------------- launch --------------------
extern "C" void kernel_launch(void* const* d_in, const int* in_sizes, int n_in,
                              void* d_out, int out_size, void* d_ws, size_t ws_size,
                              hipStream_t stream) {
  const float* x      = (const float*)d_in[0];  // [2,2048,1024]
  const float* w_qkv  = (const float*)d_in[1];  // [3072,1024]
  const float* b_qkv  = (const float*)d_in[2];  // [3072]
  const float* w_proj = (const float*)d_in[3];  // [1024,1024]
  const float* b_proj = (const float*)d_in[4];  // [1024]
  float* out = (float*)d_out;                   // [2,2048,1024]

  char* ws = (char*)d_ws;
  u16* xb     = (u16*)(ws);                       // 8 MB   [4096,1024]
  u16* wqkvb  = (u16*)(ws + (8ull  << 20));       // 6 MB   [3072,1024]
  u16* wprojb = (u16*)(ws + (14ull << 20));       // 2 MB   [1024,1024]
  u16* qkvb   = (u16*)(ws + (16ull << 20));       // 24 MB  [4096,3072]
  u16* aob    = (u16*)(ws + (40ull << 20));       // 8 MB   [4096,1024]
  // dead-after-gemm128 regions reused by attn partials (cvt rewrites them each call):
  u16*   opart0 = (u16*)(ws);                     // xb region, 8 MB
  float* lpart  = (float*)(ws + (8ull << 20));    // wqkvb region, 512 KB used

  cvt_all<<<2048, 256, 0, stream>>>(x, w_qkv, w_proj, (ushort4*)ws);

  // qkv = x @ w_qkv^T + b_qkv -> bf16 [4096,3072]; q-cols pre-scaled by 0.125*log2e
  gemm128_bt<<<512, 512, 0, stream>>>(xb, wqkvb, b_qkv, qkvb, 4096, 3072, 1024);

  // fused attention, 4-way KV split: partials (group0 -> opart0, group1 -> aob)
  attn_fused<<<1024, 512, 0, stream>>>(qkvb, opart0, aob, lpart);
  // merge partials -> normalized bf16 aob (in-place on aob is safe: read-then-write per thread)
  attn_merge<<<2048, 256, 0, stream>>>(opart0, aob, lpart, aob);

  // y = attn_out @ w_proj^T + b_proj -> fp32 d_out
  gemm_proj<<<1024, 256, 0, stream>>>(aob, wprojb, b_proj, out, 4096, 1024, 1024);
}

// Round 20
// 100.586 us; speedup vs baseline: 1.0680x; 1.0680x over previous
//
#include <hip/hip_runtime.h>
#include <hip/hip_bf16.h>

typedef __attribute__((ext_vector_type(4))) float f32x4;
typedef __attribute__((ext_vector_type(16))) float f32x16;
typedef __attribute__((ext_vector_type(8))) short short8;
typedef __attribute__((ext_vector_type(4))) unsigned int u32x4;
typedef __attribute__((ext_vector_type(2))) unsigned int u32x2;
typedef unsigned short u16;

__device__ __forceinline__ u16 f2bf(float x) {
  unsigned u = __float_as_uint(x);
  u += 0x7fffu + ((u >> 16) & 1u);   // RNE
  return (u16)(u >> 16);
}

__device__ __forceinline__ void gload_lds16(const void* g, void* l) {
  __builtin_amdgcn_global_load_lds(
      (__attribute__((address_space(1))) void*)g,
      (__attribute__((address_space(3))) void*)l, 16, 0, 0);
}

// -------------------- fp32 -> bf16 convert (all 3 inputs, one kernel) -------------
__global__ void cvt_all(const float* __restrict__ x, const float* __restrict__ wq,
                        const float* __restrict__ wp, ushort4* __restrict__ dst) {
  const int N1 = 1048576, N2 = 786432, NT = 2097152;
  for (int i = blockIdx.x * 256 + threadIdx.x; i < NT; i += 524288) {
    float4 v;
    if (i < N1)            v = ((const float4*)x)[i];
    else if (i < N1 + N2)  v = ((const float4*)wq)[i - N1];
    else                   v = ((const float4*)wp)[i - N1 - N2];
    ushort4 o;
    o.x = f2bf(v.x); o.y = f2bf(v.y); o.z = f2bf(v.z); o.w = f2bf(v.w);
    dst[i] = o;
  }
}

// ==================== 128x192 GEMM (QKV): C = A B^T + bias, bf16 out ==============
// (frozen from R13)
__global__ __launch_bounds__(512, 4) void gemm128_bt(
    const u16* __restrict__ A, const u16* __restrict__ B,
    const float* __restrict__ bias, u16* __restrict__ Cout,
    int M, int N, int K)
{
  __shared__ u16 LA[2][8192];    // [buf][128 x 64]
  __shared__ u16 LB[2][12288];   // [buf][192 x 64]

  const int tid  = threadIdx.x;
  const int w    = tid >> 6;        // 0..7
  const int lane = tid & 63;
  const int wm   = w >> 2;          // 0..1
  const int wn   = w & 3;           // 0..3
  const int hi   = lane >> 4;       // 0..3
  const int lo   = lane & 15;
  const int l7   = lo & 7;

  const int L  = (int)(blockIdx.x & 7) * 64 + (int)(blockIdx.x >> 3);
  const int bx = L >> 5, by = L & 31;
  const long brow = (long)by * 128;
  const long bcol = (long)bx * 192;

  f32x4 acc[4][3];
#pragma unroll
  for (int f = 0; f < 4; ++f)
#pragma unroll
    for (int n = 0; n < 3; ++n)
#pragma unroll
      for (int r = 0; r < 4; ++r) acc[f][n][r] = 0.0f;

  const int srow = lane >> 3;
  const int sg   = (lane & 7) ^ srow;

  auto stage = [&](int kt, int bi) {
    const long k0 = (long)kt * 64;
#pragma unroll
    for (int i = 0; i < 2; ++i) {
      const long r = brow + i * 64 + w * 8 + srow;
      gload_lds16(A + r * K + k0 + sg * 8, &LA[bi][i * 4096 + w * 512]);
    }
#pragma unroll
    for (int u = 0; u < 3; ++u) {
      const long r = bcol + u * 64 + w * 8 + srow;
      gload_lds16(B + r * K + k0 + sg * 8, &LB[bi][u * 4096 + w * 512]);
    }
  };

  const int nkt = K >> 6;   // 16
  stage(0, 0); stage(1, 1);
  asm volatile("s_waitcnt vmcnt(5)" ::: "memory");
  __builtin_amdgcn_s_barrier();

  for (int t = 0; t < nkt; ++t) {
    const int bi = t & 1;
    short8 a[4][2], b[3][2];
#pragma unroll
    for (int f = 0; f < 4; ++f) {
      const int rl = wm * 64 + f * 16 + lo;
#pragma unroll
      for (int ks = 0; ks < 2; ++ks)
        a[f][ks] = *(const short8*)(&LA[bi][rl * 64 + ((ks * 4 + hi) ^ l7) * 8]);
    }
#pragma unroll
    for (int n = 0; n < 3; ++n) {
      const int rl = wn * 48 + n * 16 + lo;
#pragma unroll
      for (int ks = 0; ks < 2; ++ks)
        b[n][ks] = *(const short8*)(&LB[bi][rl * 64 + ((ks * 4 + hi) ^ l7) * 8]);
    }
    asm volatile("s_waitcnt lgkmcnt(0)" ::: "memory");
    __builtin_amdgcn_sched_barrier(0);
    __builtin_amdgcn_s_barrier();
    if (t + 2 < nkt) stage(t + 2, bi);
    __builtin_amdgcn_s_setprio(1);
#pragma unroll
    for (int f = 0; f < 4; ++f)
#pragma unroll
      for (int n = 0; n < 3; ++n)
#pragma unroll
        for (int ks = 0; ks < 2; ++ks)
          acc[f][n] = __builtin_amdgcn_mfma_f32_16x16x32_bf16(a[f][ks], b[n][ks], acc[f][n], 0, 0, 0);
    __builtin_amdgcn_s_setprio(0);
    if (t + 2 < nkt)      { asm volatile("s_waitcnt vmcnt(5)" ::: "memory"); }
    else if (t + 1 < nkt) { asm volatile("s_waitcnt vmcnt(0)" ::: "memory"); }
    __builtin_amdgcn_sched_barrier(0);
    __builtin_amdgcn_s_barrier();
  }

  const float SCC = 0.18033688011112042f;   // 0.125 * log2(e)
  float bv[3];
#pragma unroll
  for (int n = 0; n < 3; ++n) bv[n] = bias[bcol + wn * 48 + n * 16 + lo];
#pragma unroll
  for (int f = 0; f < 4; ++f)
#pragma unroll
    for (int n = 0; n < 3; ++n) {
      const long colf = bcol + wn * 48 + n * 16;
      const float qsc = (colf < 1024) ? SCC : 1.0f;   // q/k boundary at 1024
#pragma unroll
      for (int r = 0; r < 4; ++r) {
        const long row = brow + wm * 64 + f * 16 + hi * 4 + r;
        Cout[row * (long)N + colf + lo] = f2bf((acc[f][n][r] + bv[n]) * qsc);
      }
    }
}

// ==================== 64x64 GEMM (proj): C = A B^T + bias, fp32 out ===============
// (frozen from R17)
__global__ __launch_bounds__(256, 2) void gemm_proj(
    const u16* __restrict__ A, const u16* __restrict__ B,
    const float* __restrict__ bias, float* __restrict__ Cout,
    int M, int N, int K)
{
  __shared__ u16 LA[2][4096];   // [buf][64 x 64]
  __shared__ u16 LB[2][4096];   // [buf][64 x 64]

  const int tid  = threadIdx.x;
  const int w    = tid >> 6;        // 0..3
  const int lane = tid & 63;
  const int wm   = w >> 1;
  const int wn   = w & 1;
  const int hi   = lane >> 4;
  const int lo   = lane & 15;
  const int l7   = lo & 7;

  const int L  = (int)(blockIdx.x & 7) * 128 + (int)(blockIdx.x >> 3);
  const int bx = L >> 6, by = L & 63;
  const long brow = (long)by * 64;
  const long bcol = (long)bx * 64;

  f32x4 acc[2][2];
#pragma unroll
  for (int f = 0; f < 2; ++f)
#pragma unroll
    for (int n = 0; n < 2; ++n)
#pragma unroll
      for (int r = 0; r < 4; ++r) acc[f][n][r] = 0.0f;

  const int srow = lane >> 3;
  const int sg   = (lane & 7) ^ srow;

  auto stage = [&](int kt, int bi) {
    const long k0 = (long)kt * 64;
#pragma unroll
    for (int c = 0; c < 2; ++c) {
      const long r = brow + c * 32 + w * 8 + srow;
      gload_lds16(A + r * K + k0 + sg * 8, &LA[bi][c * 2048 + w * 512]);
    }
#pragma unroll
    for (int c = 0; c < 2; ++c) {
      const long r = bcol + c * 32 + w * 8 + srow;
      gload_lds16(B + r * K + k0 + sg * 8, &LB[bi][c * 2048 + w * 512]);
    }
  };

  const int nkt = K >> 6;   // 16
  stage(0, 0); stage(1, 1);
  asm volatile("s_waitcnt vmcnt(4)" ::: "memory");
  __builtin_amdgcn_s_barrier();

  for (int t = 0; t < nkt; ++t) {
    const int bi = t & 1;
    short8 a[2][2], b[2][2];
#pragma unroll
    for (int f = 0; f < 2; ++f) {
      const int rl = wm * 32 + f * 16 + lo;
#pragma unroll
      for (int ks = 0; ks < 2; ++ks)
        a[f][ks] = *(const short8*)(&LA[bi][rl * 64 + ((ks * 4 + hi) ^ l7) * 8]);
    }
#pragma unroll
    for (int n = 0; n < 2; ++n) {
      const int rl = wn * 32 + n * 16 + lo;
#pragma unroll
      for (int ks = 0; ks < 2; ++ks)
        b[n][ks] = *(const short8*)(&LB[bi][rl * 64 + ((ks * 4 + hi) ^ l7) * 8]);
    }
    asm volatile("s_waitcnt lgkmcnt(0)" ::: "memory");
    __builtin_amdgcn_sched_barrier(0);
    __builtin_amdgcn_s_barrier();
    if (t + 2 < nkt) stage(t + 2, bi);
    __builtin_amdgcn_s_setprio(1);
#pragma unroll
    for (int f = 0; f < 2; ++f)
#pragma unroll
      for (int n = 0; n < 2; ++n)
#pragma unroll
        for (int ks = 0; ks < 2; ++ks)
          acc[f][n] = __builtin_amdgcn_mfma_f32_16x16x32_bf16(a[f][ks], b[n][ks], acc[f][n], 0, 0, 0);
    __builtin_amdgcn_s_setprio(0);
    if (t + 2 < nkt)      { asm volatile("s_waitcnt vmcnt(4)" ::: "memory"); }
    else if (t + 1 < nkt) { asm volatile("s_waitcnt vmcnt(0)" ::: "memory"); }
    __builtin_amdgcn_sched_barrier(0);
    __builtin_amdgcn_s_barrier();
  }

  float bv[2];
#pragma unroll
  for (int n = 0; n < 2; ++n) bv[n] = bias[bcol + wn * 32 + n * 16 + lo];
#pragma unroll
  for (int f = 0; f < 2; ++f)
#pragma unroll
    for (int n = 0; n < 2; ++n)
#pragma unroll
      for (int r = 0; r < 4; ++r) {
        const long row = brow + wm * 32 + f * 16 + hi * 4 + r;
        const long col = bcol + wn * 32 + n * 16 + lo;
        Cout[row * (long)N + col] = acc[f][n][r] + bv[n];
      }
}

// -------------------- fused flash attention (R10 known-good, frozen) --------------
// 8 warps = 4 q-subgroups (32 rows) x 2 KV-halves (1024 keys each).
// V single-buffered; LDS 48 KB. Shift-free softmax (Q pre-scaled at GEMM).
// Per tile: {stK(t+1) | QK(t) | softmax | vmcnt(2|0)+bar | PV(t) | vmcnt(0)+bar | stV(t+1)}
__global__ __launch_bounds__(512, 4) void attn_fused(
    const u16* __restrict__ qkv, u16* __restrict__ out)
{
  __shared__ __align__(16) char smem[49152];

  const int tid  = threadIdx.x;
  const int w    = tid >> 6;
  const int lane = tid & 63;
  const int l31  = lane & 31;
  const int hc   = lane >> 5;        // wave half
  const int g1   = (lane >> 4) & 1;  // d16 select for tr-read
  const int l15  = lane & 15;
  const int half = w >> 2;           // KV half
  const int qg   = w & 3;            // q subgroup (32 rows)

  const int bid  = blockIdx.x;
  const int xcd  = bid & 7;
  const int slot = bid >> 3;
  const int qb   = slot & 15;
  const int bh   = ((slot >> 4) << 3) | xcd;
  const int b    = bh >> 4, h = bh & 15;

  short8 qf[4];
  {
    const u16* qp = qkv + (size_t)(b * 2048 + qb * 128 + qg * 32 + l31) * 3072 + h * 64 + hc * 8;
#pragma unroll
    for (int ds = 0; ds < 4; ++ds) qf[ds] = *(const short8*)(qp + ds * 16);
  }

  f32x16 acc0, acc1;
#pragma unroll
  for (int r = 0; r < 16; ++r) { acc0[r] = 0.f; acc1[r] = 0.f; }
  float lsum = 0.f;

  const int srow8 = lane >> 3;
  const int kgl   = (lane & 7) ^ srow8;
  const int vkey  = (lane >> 5) * 4 + ((lane >> 1) & 3);
  const int vd    = ((lane >> 3) & 3) * 16 + (lane & 1) * 8;

  auto kbuf = [&](int bi) { return (u16*)(smem + (size_t)(half * 2 + bi) * 8192); };
  u16* vb = (u16*)(smem + 32768 + (size_t)half * 8192);

  auto stK = [&](int t, int bi) {
    const size_t rbase = (size_t)(b * 2048 + half * 1024 + t * 64);
    u16* Kb = kbuf(bi);
#pragma unroll
    for (int c = 0; c < 2; ++c) {
      const int chunk = qg * 2 + c;
      gload_lds16(qkv + (rbase + chunk * 8 + srow8) * 3072 + 1024 + h * 64 + kgl * 8,
                  Kb + chunk * 512);
    }
  };
  auto stV = [&](int t) {
    const size_t rbase = (size_t)(b * 2048 + half * 1024 + t * 64);
#pragma unroll
    for (int c = 0; c < 2; ++c) {
      const int chunk = qg * 2 + c;
      gload_lds16(qkv + (rbase + chunk * 8 + vkey) * 3072 + 2048 + h * 64 + vd,
                  vb + chunk * 512);
    }
  };

  stK(0, 0); stV(0);
  asm volatile("s_waitcnt vmcnt(0)" ::: "memory");
  __builtin_amdgcn_s_barrier();
  int cur = 0;

  for (int t = 0; t < 16; ++t) {
    const bool pfK = t < 15;
    if (pfK) stK(t + 1, cur ^ 1);

    const u16* Kc = kbuf(cur);

    f32x16 s0, s1;
#pragma unroll
    for (int r = 0; r < 16; ++r) { s0[r] = 0.f; s1[r] = 0.f; }
    __builtin_amdgcn_s_setprio(1);
#pragma unroll
    for (int ds = 0; ds < 4; ++ds) {
      const int gb = (((2 * ds + hc) ^ (lane & 7)) << 4);
      const short8 k0 = *(const short8*)((const char*)Kc + l31 * 128 + gb);
      const short8 k1 = *(const short8*)((const char*)Kc + 4096 + l31 * 128 + gb);
      s0 = __builtin_amdgcn_mfma_f32_32x32x16_bf16(k0, qf[ds], s0, 0, 0, 0);
      s1 = __builtin_amdgcn_mfma_f32_32x32x16_bf16(k1, qf[ds], s1, 0, 0, 0);
    }
    __builtin_amdgcn_s_setprio(0);

    float p[32];
#pragma unroll
    for (int r = 0; r < 16; ++r) {
      p[r]      = __builtin_amdgcn_exp2f(s0[r]);
      p[16 + r] = __builtin_amdgcn_exp2f(s1[r]);
    }
    {
      float a0 = 0.f, a1 = 0.f, a2 = 0.f, a3 = 0.f;
#pragma unroll
      for (int r = 0; r < 8; ++r) {
        a0 += p[r]; a1 += p[8 + r]; a2 += p[16 + r]; a3 += p[24 + r];
      }
      lsum += (a0 + a1) + (a2 + a3);
    }

    short8 pa[4];
#pragma unroll
    for (int ks = 0; ks < 4; ++ks) {
      const int bs = ks * 8;
      unsigned X0, X1, X2, X3;
      asm("v_cvt_pk_bf16_f32 %0, %1, %2" : "=v"(X0) : "v"(p[bs + 0]), "v"(p[bs + 1]));
      asm("v_cvt_pk_bf16_f32 %0, %1, %2" : "=v"(X1) : "v"(p[bs + 2]), "v"(p[bs + 3]));
      asm("v_cvt_pk_bf16_f32 %0, %1, %2" : "=v"(X2) : "v"(p[bs + 4]), "v"(p[bs + 5]));
      asm("v_cvt_pk_bf16_f32 %0, %1, %2" : "=v"(X3) : "v"(p[bs + 6]), "v"(p[bs + 7]));
      asm("v_permlane32_swap_b32 %0, %1" : "+v"(X0), "+v"(X2));
      asm("v_permlane32_swap_b32 %0, %1" : "+v"(X1), "+v"(X3));
      u32x4 wv;
      wv[0] = X0; wv[1] = X1; wv[2] = X2; wv[3] = X3;
      pa[ks] = __builtin_bit_cast(short8, wv);
    }

    if (pfK) { asm volatile("s_waitcnt vmcnt(2)" ::: "memory"); }
    else     { asm volatile("s_waitcnt vmcnt(0)" ::: "memory"); }
    __builtin_amdgcn_sched_barrier(0);
    __builtin_amdgcn_s_barrier();

    {
      const unsigned va =
          (unsigned)(unsigned long long)(const __attribute__((address_space(3))) u16*)vb;
#pragma unroll
      for (int dt = 0; dt < 2; ++dt) {
        const unsigned vba = va + (unsigned)(hc * 1024 + dt * 256 + g1 * 128 + l15 * 8);
        u32x2 q0, q1, q2, q3, q4, q5, q6, q7;
        asm volatile("ds_read_b64_tr_b16 %0, %1"             : "=v"(q0) : "v"(vba));
        asm volatile("ds_read_b64_tr_b16 %0, %1 offset:512"  : "=v"(q1) : "v"(vba));
        asm volatile("ds_read_b64_tr_b16 %0, %1 offset:2048" : "=v"(q2) : "v"(vba));
        asm volatile("ds_read_b64_tr_b16 %0, %1 offset:2560" : "=v"(q3) : "v"(vba));
        asm volatile("ds_read_b64_tr_b16 %0, %1 offset:4096" : "=v"(q4) : "v"(vba));
        asm volatile("ds_read_b64_tr_b16 %0, %1 offset:4608" : "=v"(q5) : "v"(vba));
        asm volatile("ds_read_b64_tr_b16 %0, %1 offset:6144" : "=v"(q6) : "v"(vba));
        asm volatile("ds_read_b64_tr_b16 %0, %1 offset:6656" : "=v"(q7) : "v"(vba));
        asm volatile("s_waitcnt lgkmcnt(0)" ::: "memory");
        __builtin_amdgcn_sched_barrier(0);
        __builtin_amdgcn_s_setprio(1);
        f32x16 A = dt ? acc1 : acc0;
        {
          u32x4 bb; bb[0] = q0[0]; bb[1] = q0[1]; bb[2] = q1[0]; bb[3] = q1[1];
          A = __builtin_amdgcn_mfma_f32_32x32x16_bf16(pa[0], __builtin_bit_cast(short8, bb), A, 0, 0, 0);
        }
        {
          u32x4 bb; bb[0] = q2[0]; bb[1] = q2[1]; bb[2] = q3[0]; bb[3] = q3[1];
          A = __builtin_amdgcn_mfma_f32_32x32x16_bf16(pa[1], __builtin_bit_cast(short8, bb), A, 0, 0, 0);
        }
        {
          u32x4 bb; bb[0] = q4[0]; bb[1] = q4[1]; bb[2] = q5[0]; bb[3] = q5[1];
          A = __builtin_amdgcn_mfma_f32_32x32x16_bf16(pa[2], __builtin_bit_cast(short8, bb), A, 0, 0, 0);
        }
        {
          u32x4 bb; bb[0] = q6[0]; bb[1] = q6[1]; bb[2] = q7[0]; bb[3] = q7[1];
          A = __builtin_amdgcn_mfma_f32_32x32x16_bf16(pa[3], __builtin_bit_cast(short8, bb), A, 0, 0, 0);
        }
        __builtin_amdgcn_s_setprio(0);
        if (dt) acc1 = A; else acc0 = A;
      }
    }

    asm volatile("s_waitcnt vmcnt(0)" ::: "memory");
    __builtin_amdgcn_sched_barrier(0);
    __builtin_amdgcn_s_barrier();

    if (pfK) stV(t + 1);
    cur ^= 1;
  }

  float ltot = lsum + __shfl_xor(lsum, 32);
  float* MG = (float*)smem;
  const int midx = (qg * 64 + lane) * 33;
  if (half == 1) {
#pragma unroll
    for (int r = 0; r < 16; ++r) { MG[midx + r] = acc0[r]; MG[midx + 16 + r] = acc1[r]; }
    MG[midx + 32] = ltot;
  }
  __syncthreads();
  if (half == 0) {
#pragma unroll
    for (int r = 0; r < 16; ++r) { acc0[r] += MG[midx + r]; acc1[r] += MG[midx + 16 + r]; }
    ltot += MG[midx + 32];
    const float inv = 1.0f / ltot;
    const size_t orow0 = (size_t)(b * 2048 + qb * 128 + qg * 32);
#pragma unroll
    for (int r = 0; r < 16; ++r) {
      const int rowq = (r & 3) + 8 * (r >> 2) + 4 * hc;
      const float ir = __shfl(inv, rowq);
      out[(orow0 + rowq) * 1024 + h * 64 + l31]      = f2bf(acc0[r] * ir);
      out[(orow0 + rowq) * 1024 + h * 64 + 32 + l31] = f2bf(acc1[r] * ir);
    }
  }
}

// -------------------- launch --------------------
extern "C" void kernel_launch(void* const* d_in, const int* in_sizes, int n_in,
                              void* d_out, int out_size, void* d_ws, size_t ws_size,
                              hipStream_t stream) {
  const float* x      = (const float*)d_in[0];  // [2,2048,1024]
  const float* w_qkv  = (const float*)d_in[1];  // [3072,1024]
  const float* b_qkv  = (const float*)d_in[2];  // [3072]
  const float* w_proj = (const float*)d_in[3];  // [1024,1024]
  const float* b_proj = (const float*)d_in[4];  // [1024]
  float* out = (float*)d_out;                   // [2,2048,1024]

  char* ws = (char*)d_ws;
  u16* xb     = (u16*)(ws);                       // 8 MB   [4096,1024]
  u16* wqkvb  = (u16*)(ws + (8ull  << 20));       // 6 MB   [3072,1024]
  u16* wprojb = (u16*)(ws + (14ull << 20));       // 2 MB   [1024,1024]
  u16* qkvb   = (u16*)(ws + (16ull << 20));       // 24 MB  [4096,3072]
  u16* aob    = (u16*)(ws + (40ull << 20));       // 8 MB   [4096,1024]

  cvt_all<<<2048, 256, 0, stream>>>(x, w_qkv, w_proj, (ushort4*)ws);

  // qkv = x @ w_qkv^T + b_qkv -> bf16 [4096,3072]; q-cols pre-scaled by 0.125*log2e
  gemm128_bt<<<512, 512, 0, stream>>>(xb, wqkvb, b_qkv, qkvb, 4096, 3072, 1024);

  // fused attention -> bf16 [4096,1024] (R10 known-good, frozen)
  attn_fused<<<512, 512, 0, stream>>>(qkvb, aob);

  // y = attn_out @ w_proj^T + b_proj -> fp32 d_out (64x64 tiles, 1024 blocks = 4/CU)
  gemm_proj<<<1024, 256, 0, stream>>>(aob, wprojb, b_proj, out, 4096, 1024, 1024);
}